// Round 1
// baseline (691.756 us; speedup 1.0000x reference)
//
#include <hip/hip_runtime.h>
#include <math.h>

// Problem: B=64, S=2048, H=1024. Single-query attention + concat.
// out[b, 0:H]    = h_n[b]
// out[b, H:2H]   = softmax_s(h_n[b]·enc[b,s,:]) @ enc[b,:,:]
//
// Memory-bound: enc is 537 MB; single-pass online softmax reads it once.
//
// v2 changes vs 674µs baseline:
//  1. STRIDED row->chunk mapping (s = chunk + 16*j instead of contiguous
//     128-row slabs). The old mapping made every block 512KB-aligned and
//     phase-locked => all 1024 blocks presented identical low-19 addr bits
//     at every instant => HBM channel camping at ~1.6 TB/s. The comb
//     mapping spreads active addresses across all row phases (bits 12..18
//     vary per block/wave) => uniform channel load. Softmax is
//     order-invariant, so the math is unchanged.
//  2. 2 rows per wave-iteration: halves butterfly ds-ops per row, fuses
//     the online-softmax rescale (3 FMA/elem per 2 rows), 8KB in flight.

#define BB 64
#define SS 2048
#define HH 1024
#define NCHUNK 16               // chunks per batch -> 64*16 = 1024 blocks
#define JCOUNT (SS / NCHUNK)    // 128 rows per chunk (strided by NCHUNK)
#define NWAVE 4                 // 256 threads
#define RPI 2                   // rows per wave-iteration
#define NITER (JCOUNT / (NWAVE * RPI))   // 16

// ws layout:
//   [0 .. B*NCHUNK*H)              : partial ctx accumulators (float), 4.19 MB
//   [B*NCHUNK*H .. +B*NCHUNK*2)    : (m, l) pairs per partial
#define WS_ML_OFF ((size_t)BB * NCHUNK * HH)

__global__ __launch_bounds__(256, 4) void attn_partial_kernel(
    const float* __restrict__ enc, const float* __restrict__ hn,
    float* __restrict__ ws)
{
    const int blk   = blockIdx.x;          // b * NCHUNK + chunk
    const int b     = blk / NCHUNK;
    const int chunk = blk % NCHUNK;
    const int tid   = threadIdx.x;
    const int wave  = tid >> 6;
    const int lane  = tid & 63;

    // Preload this lane's 16 h_n elements: h = j*256 + lane*4 + c
    const float4* hn4 = (const float4*)(hn + (size_t)b * HH);
    float4 h4[4];
#pragma unroll
    for (int j = 0; j < 4; ++j) h4[j] = hn4[j * 64 + lane];

    const float4* enc4 = (const float4*)(enc + (size_t)b * SS * HH);

    float m = -INFINITY;
    float l = 0.0f;
    float4 acc[4];
#pragma unroll
    for (int j = 0; j < 4; ++j) acc[j] = make_float4(0.f, 0.f, 0.f, 0.f);

    for (int k = 0; k < NITER; ++k) {
        // j-indices jj, jj+1; rows s_r = chunk + NCHUNK*(jj+r)
        const int jj = (k * NWAVE + wave) * RPI;
        const float4* r0 = enc4 + (size_t)(chunk + NCHUNK * (jj + 0)) * (HH / 4);
        const float4* r1 = enc4 + (size_t)(chunk + NCHUNK * (jj + 1)) * (HH / 4);

        float4 e0[4], e1[4];
#pragma unroll
        for (int j = 0; j < 4; ++j) e0[j] = r0[j * 64 + lane];
#pragma unroll
        for (int j = 0; j < 4; ++j) e1[j] = r1[j * 64 + lane];

        // two dots, 2 partial accumulators each (shorter dep chains)
        float d0a = 0.f, d0b = 0.f, d1a = 0.f, d1b = 0.f;
#pragma unroll
        for (int j = 0; j < 2; ++j) {
            d0a += e0[j].x * h4[j].x + e0[j].y * h4[j].y
                 + e0[j].z * h4[j].z + e0[j].w * h4[j].w;
            d1a += e1[j].x * h4[j].x + e1[j].y * h4[j].y
                 + e1[j].z * h4[j].z + e1[j].w * h4[j].w;
        }
#pragma unroll
        for (int j = 2; j < 4; ++j) {
            d0b += e0[j].x * h4[j].x + e0[j].y * h4[j].y
                 + e0[j].z * h4[j].z + e0[j].w * h4[j].w;
            d1b += e1[j].x * h4[j].x + e1[j].y * h4[j].y
                 + e1[j].z * h4[j].z + e1[j].w * h4[j].w;
        }
        float d0 = d0a + d0b;
        float d1 = d1a + d1b;

        // wave-64 butterfly reduce, two rows interleaved (latency overlap)
#pragma unroll
        for (int off = 32; off > 0; off >>= 1) {
            d0 += __shfl_xor(d0, off, 64);
            d1 += __shfl_xor(d1, off, 64);
        }

        // fused online softmax update for both rows
        const float m_new = fmaxf(m, fmaxf(d0, d1));
        const float scale = __expf(m - m_new);   // first iter: exp(-inf)=0
        const float p0    = __expf(d0 - m_new);
        const float p1    = __expf(d1 - m_new);
        l = l * scale + p0 + p1;
#pragma unroll
        for (int j = 0; j < 4; ++j) {
            acc[j].x = fmaf(acc[j].x, scale, fmaf(p0, e0[j].x, p1 * e1[j].x));
            acc[j].y = fmaf(acc[j].y, scale, fmaf(p0, e0[j].y, p1 * e1[j].y));
            acc[j].z = fmaf(acc[j].z, scale, fmaf(p0, e0[j].z, p1 * e1[j].z));
            acc[j].w = fmaf(acc[j].w, scale, fmaf(p0, e0[j].w, p1 * e1[j].w));
        }
        m = m_new;
    }

    // ---- combine 4 wave-partials within the block via LDS ----
    __shared__ float s_m[NWAVE];
    __shared__ float s_l[NWAVE];
    __shared__ float s_acc[NWAVE][HH];     // 16 KB

#pragma unroll
    for (int j = 0; j < 4; ++j)
        ((float4*)s_acc[wave])[j * 64 + lane] = acc[j];
    if (lane == 0) { s_m[wave] = m; s_l[wave] = l; }
    __syncthreads();

    float M = fmaxf(fmaxf(s_m[0], s_m[1]), fmaxf(s_m[2], s_m[3]));
    float sc[NWAVE];
    float L = 0.0f;
#pragma unroll
    for (int w = 0; w < NWAVE; ++w) {
        sc[w] = __expf(s_m[w] - M);
        L += s_l[w] * sc[w];
    }

    // each thread finalizes one float4 slot (tid covers 256 slots = 1024 floats)
    float4 ctx = make_float4(0.f, 0.f, 0.f, 0.f);
#pragma unroll
    for (int w = 0; w < NWAVE; ++w) {
        float4 a = ((const float4*)s_acc[w])[tid];
        ctx.x += sc[w] * a.x;  ctx.y += sc[w] * a.y;
        ctx.z += sc[w] * a.z;  ctx.w += sc[w] * a.w;
    }
    ((float4*)(ws + (size_t)blk * HH))[tid] = ctx;
    if (tid == 0) {
        ws[WS_ML_OFF + (size_t)blk * 2 + 0] = M;
        ws[WS_ML_OFF + (size_t)blk * 2 + 1] = L;
    }
}

__global__ __launch_bounds__(256) void attn_final_kernel(
    const float* __restrict__ hn, const float* __restrict__ ws,
    float* __restrict__ out)
{
    const int b   = blockIdx.x;
    const int tid = threadIdx.x;
    const float* ml = ws + WS_ML_OFF + (size_t)b * NCHUNK * 2;

    float M = -INFINITY;
#pragma unroll
    for (int c = 0; c < NCHUNK; ++c) M = fmaxf(M, ml[c * 2]);

    float sc[NCHUNK];
    float T = 0.0f;
#pragma unroll
    for (int c = 0; c < NCHUNK; ++c) {
        sc[c] = __expf(ml[c * 2] - M);
        T += sc[c] * ml[c * 2 + 1];
    }
    const float invT = 1.0f / T;

    float4 ctx = make_float4(0.f, 0.f, 0.f, 0.f);
#pragma unroll
    for (int c = 0; c < NCHUNK; ++c) {
        float4 a = ((const float4*)(ws + (size_t)(b * NCHUNK + c) * HH))[tid];
        ctx.x += sc[c] * a.x;  ctx.y += sc[c] * a.y;
        ctx.z += sc[c] * a.z;  ctx.w += sc[c] * a.w;
    }
    ctx.x *= invT; ctx.y *= invT; ctx.z *= invT; ctx.w *= invT;

    const float4 dec = ((const float4*)(hn + (size_t)b * HH))[tid];
    float4* o = (float4*)(out + (size_t)b * 2 * HH);
    o[tid]            = dec;   // dec_output half
    o[tid + (HH / 4)] = ctx;   // context half
}

extern "C" void kernel_launch(void* const* d_in, const int* in_sizes, int n_in,
                              void* d_out, int out_size, void* d_ws, size_t ws_size,
                              hipStream_t stream) {
    const float* enc = (const float*)d_in[0];   // (B, S, H) fp32
    const float* hn  = (const float*)d_in[1];   // (B, H) fp32
    float* out = (float*)d_out;                 // (B, 1, 2H) fp32
    float* ws  = (float*)d_ws;

    attn_partial_kernel<<<dim3(BB * NCHUNK), dim3(256), 0, stream>>>(enc, hn, ws);
    attn_final_kernel<<<dim3(BB), dim3(256), 0, stream>>>(hn, ws, out);
}

// Round 3
// 642.161 us; speedup vs baseline: 1.0772x; 1.0772x over previous
//
#include <hip/hip_runtime.h>
#include <math.h>

// Problem: B=64, S=2048, H=1024. Single-query attention + concat.
// out[b, 0:H]    = h_n[b]
// out[b, H:2H]   = softmax_s(h_n[b]·enc[b,s,:]) @ enc[b,:,:]
//
// Memory-bound: enc is 537 MB; single-pass online softmax reads it once.
//
// v3b (round 3): identical to v3, with the nontemporal load fixed to use
// a clang ext_vector type (the builtin rejects HIP_vector_type).
//  1. Per-block START-ROW ROTATION. Round-0 phase-locked all 1024 blocks:
//     every block base is 512KB-aligned and all blocks advance through
//     identical intra-slab offsets => identical low ~19 addr bits across
//     the machine at every instant => HBM channel camping (~1.6 TB/s).
//     Rotating each block's walk by (blk*53 mod 128) rows spreads the
//     instantaneous row-phases over all 128 positions. Round-1's 64KB-
//     stride comb made things WORSE (constant stride camps by itself),
//     so we keep the contiguous walk and only rotate its starting point.
//     Softmax is order-invariant => math unchanged.
//  2. Nontemporal enc loads: zero-reuse stream; avoid L3 allocation and
//     dirty-line churn.

#define BB 64
#define SS 2048
#define HH 1024
#define NCHUNK 16              // S-chunks per batch -> 64*16 = 1024 blocks
#define SCHUNK (SS / NCHUNK)   // 128 rows per block
#define NWAVE 4                // 256 threads

typedef float fvec4 __attribute__((ext_vector_type(4)));

// ws layout:
//   [0 .. B*NCHUNK*H)              : partial ctx accumulators (float), 4.19 MB
//   [B*NCHUNK*H .. +B*NCHUNK*2)    : (m, l) pairs per partial
#define WS_ML_OFF ((size_t)BB * NCHUNK * HH)

__global__ __launch_bounds__(256) void attn_partial_kernel(
    const float* __restrict__ enc, const float* __restrict__ hn,
    float* __restrict__ ws)
{
    const int blk   = blockIdx.x;          // b * NCHUNK + chunk
    const int b     = blk / NCHUNK;
    const int chunk = blk % NCHUNK;
    const int tid   = threadIdx.x;
    const int wave  = tid >> 6;
    const int lane  = tid & 63;

    // Preload this lane's 16 h_n elements: h = j*256 + lane*4 + c
    const fvec4* hn4 = (const fvec4*)(hn + (size_t)b * HH);
    fvec4 h4[4];
#pragma unroll
    for (int j = 0; j < 4; ++j) h4[j] = hn4[j * 64 + lane];

    const fvec4* enc4 = (const fvec4*)(enc + (size_t)b * SS * HH);

    float m = -INFINITY;
    float l = 0.0f;
    fvec4 acc[4];
#pragma unroll
    for (int j = 0; j < 4; ++j) acc[j] = (fvec4)(0.f, 0.f, 0.f, 0.f);

    const int s0    = chunk * SCHUNK;
    const int start = (blk * 53) & (SCHUNK - 1);   // per-block phase rotation

    for (int k = 0; k < SCHUNK / NWAVE; ++k) {
        const int r = (start + wave + NWAVE * k) & (SCHUNK - 1);
        const fvec4* row = enc4 + (size_t)(s0 + r) * (HH / 4);
        fvec4 e[4];
#pragma unroll
        for (int j = 0; j < 4; ++j)
            e[j] = __builtin_nontemporal_load(&row[j * 64 + lane]);

        float d = 0.0f;
#pragma unroll
        for (int j = 0; j < 4; ++j) {
            d += e[j].x * h4[j].x + e[j].y * h4[j].y
               + e[j].z * h4[j].z + e[j].w * h4[j].w;
        }
        // wave-64 butterfly reduce
#pragma unroll
        for (int off = 32; off > 0; off >>= 1)
            d += __shfl_xor(d, off, 64);

        // online softmax update
        const float m_new = fmaxf(m, d);
        const float scale = __expf(m - m_new);   // first iter: exp(-inf)=0
        const float p     = __expf(d - m_new);
        l = l * scale + p;
#pragma unroll
        for (int j = 0; j < 4; ++j) {
            acc[j].x = acc[j].x * scale + p * e[j].x;
            acc[j].y = acc[j].y * scale + p * e[j].y;
            acc[j].z = acc[j].z * scale + p * e[j].z;
            acc[j].w = acc[j].w * scale + p * e[j].w;
        }
        m = m_new;
    }

    // ---- combine 4 wave-partials within the block via LDS ----
    __shared__ float s_m[NWAVE];
    __shared__ float s_l[NWAVE];
    __shared__ float s_acc[NWAVE][HH];     // 16 KB

#pragma unroll
    for (int j = 0; j < 4; ++j)
        ((fvec4*)s_acc[wave])[j * 64 + lane] = acc[j];
    if (lane == 0) { s_m[wave] = m; s_l[wave] = l; }
    __syncthreads();

    float M = fmaxf(fmaxf(s_m[0], s_m[1]), fmaxf(s_m[2], s_m[3]));
    float sc[NWAVE];
    float L = 0.0f;
#pragma unroll
    for (int w = 0; w < NWAVE; ++w) {
        sc[w] = __expf(s_m[w] - M);
        L += s_l[w] * sc[w];
    }

    // each thread finalizes one fvec4 slot (tid covers 256 slots = 1024 floats)
    fvec4 ctx = (fvec4)(0.f, 0.f, 0.f, 0.f);
#pragma unroll
    for (int w = 0; w < NWAVE; ++w) {
        fvec4 a = ((const fvec4*)s_acc[w])[tid];
        ctx.x += sc[w] * a.x;  ctx.y += sc[w] * a.y;
        ctx.z += sc[w] * a.z;  ctx.w += sc[w] * a.w;
    }
    ((fvec4*)(ws + (size_t)blk * HH))[tid] = ctx;
    if (tid == 0) {
        ws[WS_ML_OFF + (size_t)blk * 2 + 0] = M;
        ws[WS_ML_OFF + (size_t)blk * 2 + 1] = L;
    }
}

__global__ __launch_bounds__(256) void attn_final_kernel(
    const float* __restrict__ hn, const float* __restrict__ ws,
    float* __restrict__ out)
{
    const int b   = blockIdx.x;
    const int tid = threadIdx.x;
    const float* ml = ws + WS_ML_OFF + (size_t)b * NCHUNK * 2;

    float M = -INFINITY;
#pragma unroll
    for (int c = 0; c < NCHUNK; ++c) M = fmaxf(M, ml[c * 2]);

    float sc[NCHUNK];
    float T = 0.0f;
#pragma unroll
    for (int c = 0; c < NCHUNK; ++c) {
        sc[c] = __expf(ml[c * 2] - M);
        T += sc[c] * ml[c * 2 + 1];
    }
    const float invT = 1.0f / T;

    fvec4 ctx = (fvec4)(0.f, 0.f, 0.f, 0.f);
#pragma unroll
    for (int c = 0; c < NCHUNK; ++c) {
        fvec4 a = ((const fvec4*)(ws + (size_t)(b * NCHUNK + c) * HH))[tid];
        ctx.x += sc[c] * a.x;  ctx.y += sc[c] * a.y;
        ctx.z += sc[c] * a.z;  ctx.w += sc[c] * a.w;
    }
    ctx.x *= invT; ctx.y *= invT; ctx.z *= invT; ctx.w *= invT;

    const fvec4 dec = ((const fvec4*)(hn + (size_t)b * HH))[tid];
    fvec4* o = (fvec4*)(out + (size_t)b * 2 * HH);
    o[tid]            = dec;   // dec_output half
    o[tid + (HH / 4)] = ctx;   // context half
}

extern "C" void kernel_launch(void* const* d_in, const int* in_sizes, int n_in,
                              void* d_out, int out_size, void* d_ws, size_t ws_size,
                              hipStream_t stream) {
    const float* enc = (const float*)d_in[0];   // (B, S, H) fp32
    const float* hn  = (const float*)d_in[1];   // (B, H) fp32
    float* out = (float*)d_out;                 // (B, 1, 2H) fp32
    float* ws  = (float*)d_ws;

    attn_partial_kernel<<<dim3(BB * NCHUNK), dim3(256), 0, stream>>>(enc, hn, ws);
    attn_final_kernel<<<dim3(BB), dim3(256), 0, stream>>>(hn, ws, out);
}